// Round 1
// baseline (2837.336 us; speedup 1.0000x reference)
//
#include <hip/hip_runtime.h>

// SGGCN forward:
//  p0 = scatter_add(x[src]*w -> dst);  h1 = relu(bn(p0 @ W1.T + b1))
//  p1 = scatter_add(h1[src]*w -> dst); h  = relu(bn(p1 @ W2.T + b2))   (output 1)
//  z  = relu(h @ pW1.T + pb1) @ pW2.T + pb2                            (output 2)
//  logits = scatter_add(h[src]*w -> dst) @ W3.T + b3                   (output 0)

#define NF 128

// ---------------- scatter-add propagate ----------------
// 2 edges per 256-thread block; one float feature per thread; HW fp32 atomic.
__global__ __launch_bounds__(256) void scatter_add_k(
    const float* __restrict__ h, const int* __restrict__ ei,
    const float* __restrict__ ew, float* __restrict__ p, int E)
{
    int e = blockIdx.x * 2 + (threadIdx.x >> 7);
    if (e >= E) return;
    int f = threadIdx.x & 127;
    int s = ei[e];        // src row
    int d = ei[E + e];    // dst row
    float v = h[(size_t)s * NF + f] * ew[e];
    unsafeAtomicAdd(&p[(size_t)d * NF + f], v);
}

// ---------------- fp32 GEMM, C[N,M] = A[N,128] @ W[M,128]^T + b ----------------
// 64-row tile per block, full M per block, K chunked by 64.
// LDS: At[k][row] (64x68) + Wt[k][col] (64x(M+4))  -> 51.2KB for M=128.
template <int M>
__global__ __launch_bounds__(256) void gemm_k128(
    const float* __restrict__ A, const float* __restrict__ W,
    const float* __restrict__ bias, float* __restrict__ C,
    int N, int relu)
{
    constexpr int CPT = M / 16;       // cols per thread: 8 (M=128) or 4 (M=64)
    __shared__ float At[64][68];      // [k][row], padded
    __shared__ float Wt[64][M + 4];   // [k][col], padded

    const int tid  = threadIdx.x;
    const int row0 = blockIdx.x * 64;
    const int tr   = tid >> 4;        // 0..15 -> rows tr*4..tr*4+3
    const int tc   = tid & 15;        // cols tc*CPT..

    float acc[4][CPT];
#pragma unroll
    for (int i = 0; i < 4; i++)
#pragma unroll
        for (int j = 0; j < CPT; j++) acc[i][j] = 0.f;

    for (int kc = 0; kc < 128; kc += 64) {
        // load W chunk transposed (coalesced global read along k)
        for (int idx = tid; idx < M * 64; idx += 256) {
            int o = idx >> 6, k = idx & 63;
            Wt[k][o] = W[o * 128 + kc + k];
        }
        // load A tile transposed
        for (int idx = tid; idx < 64 * 64; idx += 256) {
            int r = idx >> 6, k = idx & 63;
            int gr = row0 + r;
            At[k][r] = (gr < N) ? A[(size_t)gr * 128 + kc + k] : 0.f;
        }
        __syncthreads();

#pragma unroll 8
        for (int k = 0; k < 64; ++k) {
            float4 a4 = *(const float4*)&At[k][tr * 4];
            float av[4] = {a4.x, a4.y, a4.z, a4.w};
            float wv[CPT];
            {
                float4 w0 = *(const float4*)&Wt[k][tc * CPT];
                wv[0] = w0.x; wv[1] = w0.y; wv[2] = w0.z; wv[3] = w0.w;
                if constexpr (CPT == 8) {
                    float4 w1 = *(const float4*)&Wt[k][tc * CPT + 4];
                    wv[4] = w1.x; wv[5] = w1.y; wv[6] = w1.z; wv[7] = w1.w;
                }
            }
#pragma unroll
            for (int i = 0; i < 4; i++)
#pragma unroll
                for (int j = 0; j < CPT; j++)
                    acc[i][j] = fmaf(av[i], wv[j], acc[i][j]);
        }
        __syncthreads();
    }

    // epilogue
#pragma unroll
    for (int i = 0; i < 4; i++) {
        int gr = row0 + tr * 4 + i;
        if (gr >= N) continue;
#pragma unroll
        for (int j = 0; j < CPT; j++) {
            int col = tc * CPT + j;
            float v = acc[i][j] + bias[col];
            if (relu) v = fmaxf(v, 0.f);
            C[(size_t)gr * M + col] = v;
        }
    }
}

// ---------------- per-column sum / sumsq over N rows ----------------
__global__ __launch_bounds__(256) void colstats_k(
    const float* __restrict__ A, float* __restrict__ stats, int N)
{
    int col  = threadIdx.x & 127;
    int rsub = threadIdx.x >> 7;
    float s = 0.f, s2 = 0.f;
    for (int r = blockIdx.x * 2 + rsub; r < N; r += gridDim.x * 2) {
        float v = A[(size_t)r * NF + col];
        s += v; s2 += v * v;
    }
    unsafeAtomicAdd(&stats[col], s);
    unsafeAtomicAdd(&stats[NF + col], s2);
}

// ---------------- BN (train stats, biased var) + affine + ReLU ----------------
__global__ __launch_bounds__(256) void bn_relu_k(
    const float* __restrict__ src, const float* __restrict__ stats,
    const float* __restrict__ g, const float* __restrict__ be,
    float* __restrict__ dst, int total, float invN)
{
    int idx = blockIdx.x * 256 + threadIdx.x;
    if (idx >= total) return;
    int col = idx & 127;
    float m  = stats[col] * invN;
    float var = stats[NF + col] * invN - m * m;
    float rs = rsqrtf(var + 1e-5f);
    float v  = (src[idx] - m) * rs * g[col] + be[col];
    dst[idx] = fmaxf(v, 0.f);
}

extern "C" void kernel_launch(void* const* d_in, const int* in_sizes, int n_in,
                              void* d_out, int out_size, void* d_ws, size_t ws_size,
                              hipStream_t stream)
{
    const float* x   = (const float*)d_in[0];
    const int*   ei  = (const int*)d_in[1];
    const float* ew  = (const float*)d_in[2];
    const float* W1  = (const float*)d_in[3];
    const float* b1  = (const float*)d_in[4];
    const float* W2  = (const float*)d_in[5];
    const float* b2  = (const float*)d_in[6];
    const float* W3  = (const float*)d_in[7];
    const float* b3  = (const float*)d_in[8];
    const float* g1  = (const float*)d_in[9];
    const float* be1 = (const float*)d_in[10];
    const float* g2  = (const float*)d_in[11];
    const float* be2 = (const float*)d_in[12];
    const float* pW1 = (const float*)d_in[13];
    const float* pb1 = (const float*)d_in[14];
    const float* pW2 = (const float*)d_in[15];
    const float* pb2 = (const float*)d_in[16];

    const int N = in_sizes[0] / NF;
    const int E = in_sizes[2];

    float* out_logits = (float*)d_out;
    float* out_h      = out_logits + (size_t)N * 64;
    float* out_z      = out_h + (size_t)N * NF;

    float* p     = (float*)d_ws;
    float* hpre  = p + (size_t)N * NF;
    float* stats = hpre + (size_t)N * NF;

    const size_t matBytes = (size_t)N * NF * sizeof(float);
    const dim3 sgrid((E + 1) / 2);
    const int  ggrid = (N + 63) / 64;
    const int  egrid = (N * NF + 255) / 256;
    const float invN = 1.f / (float)N;

    // ---- layer 1 ----
    hipMemsetAsync(p, 0, matBytes, stream);
    scatter_add_k<<<sgrid, 256, 0, stream>>>(x, ei, ew, p, E);
    gemm_k128<128><<<ggrid, 256, 0, stream>>>(p, W1, b1, hpre, N, 0);
    hipMemsetAsync(stats, 0, 2 * NF * sizeof(float), stream);
    colstats_k<<<2048, 256, 0, stream>>>(hpre, stats, N);
    bn_relu_k<<<egrid, 256, 0, stream>>>(hpre, stats, g1, be1, hpre, N * NF, invN);

    // ---- layer 2 ----
    hipMemsetAsync(p, 0, matBytes, stream);
    scatter_add_k<<<sgrid, 256, 0, stream>>>(hpre, ei, ew, p, E);
    gemm_k128<128><<<ggrid, 256, 0, stream>>>(p, W2, b2, hpre, N, 0);
    hipMemsetAsync(stats, 0, 2 * NF * sizeof(float), stream);
    colstats_k<<<2048, 256, 0, stream>>>(hpre, stats, N);
    bn_relu_k<<<egrid, 256, 0, stream>>>(hpre, stats, g2, be2, out_h, N * NF, invN);

    // ---- proj MLP: z = relu(h@pW1.T+pb1) @ pW2.T + pb2 ----
    gemm_k128<128><<<ggrid, 256, 0, stream>>>(out_h, pW1, pb1, hpre, N, 1);
    gemm_k128<128><<<ggrid, 256, 0, stream>>>(hpre, pW2, pb2, out_z, N, 0);

    // ---- logits = propagate(h) @ W3.T + b3 ----
    hipMemsetAsync(p, 0, matBytes, stream);
    scatter_add_k<<<sgrid, 256, 0, stream>>>(out_h, ei, ew, p, E);
    gemm_k128<64><<<ggrid, 256, 0, stream>>>(p, W3, b3, out_logits, N, 0);
}

// Round 2
// 1272.079 us; speedup vs baseline: 2.2305x; 2.2305x over previous
//
#include <hip/hip_runtime.h>

// SGGCN forward, CSR-gather version:
//  CSR build (per launch): deg histogram -> scan -> atomic-cursor fill
//  p = gather-sum over CSR (optionally with fused BN+ReLU on the *input* rows)
//  GEMM fp32 (LDS-tiled) with optional fused column sum/sumsq stats epilogue
//
//  p0 = gather(x);          pre1 = p0 @ W1.T + b1   (+stats1)
//  p1 = gather(bnrelu1(pre1)) [BN fused into gather load]
//  pre2 = p1 @ W2.T + b2    (+stats2)
//  out_h = bnrelu2(pre2)
//  z = relu(out_h @ pW1.T + pb1) @ pW2.T + pb2
//  logits = gather(out_h) @ W3.T + b3

#define NF 128

// ================= CSR build =================
__global__ __launch_bounds__(256) void deg_k(const int* __restrict__ ei,
                                             int* __restrict__ deg, int E)
{
    int e = blockIdx.x * 256 + threadIdx.x;
    if (e < E) atomicAdd(&deg[ei[E + e]], 1);
}

// per-block scan of 1024 elements (4/thread), exclusive result + block total
__global__ __launch_bounds__(256) void scan1_k(const int* __restrict__ deg,
                                               int* __restrict__ off,
                                               int* __restrict__ bsum, int N)
{
    __shared__ int part[256];
    int t = threadIdx.x;
    int base = blockIdx.x * 1024 + t * 4;
    int v[4], s = 0;
#pragma unroll
    for (int i = 0; i < 4; i++) {
        int idx = base + i;
        v[i] = (idx < N) ? deg[idx] : 0;
        s += v[i];
    }
    part[t] = s;
    __syncthreads();
    for (int ofs = 1; ofs < 256; ofs <<= 1) {
        int x = (t >= ofs) ? part[t - ofs] : 0;
        __syncthreads();
        part[t] += x;
        __syncthreads();
    }
    int run = part[t] - s;  // exclusive prefix for this thread
#pragma unroll
    for (int i = 0; i < 4; i++) {
        int idx = base + i;
        if (idx < N) off[idx] = run;
        run += v[i];
    }
    if (t == 0) bsum[blockIdx.x] = part[255];
}

__global__ void scan2_k(int* __restrict__ bsum, int NB)
{
    __shared__ int tmp[256];
    int t = threadIdx.x;
    if (t < NB) tmp[t] = bsum[t];
    __syncthreads();
    if (t == 0) {
        int acc = 0;
        for (int i = 0; i < NB; i++) { int x = tmp[i]; tmp[i] = acc; acc += x; }
    }
    __syncthreads();
    if (t < NB) bsum[t] = tmp[t];
}

__global__ __launch_bounds__(256) void scan3_k(int* __restrict__ off,
                                               int* __restrict__ cursor,
                                               const int* __restrict__ bsum,
                                               int N, int E)
{
    int idx = blockIdx.x * 256 + threadIdx.x;
    if (idx < N) {
        int o = off[idx] + bsum[idx >> 10];
        off[idx] = o;
        cursor[idx] = o;
    }
    if (idx == 0) off[N] = E;
}

__global__ __launch_bounds__(256) void fill_k(const int* __restrict__ ei,
                                              const float* __restrict__ ew,
                                              int* __restrict__ cursor,
                                              int* __restrict__ esrc,
                                              float* __restrict__ ewt, int E)
{
    int e = blockIdx.x * 256 + threadIdx.x;
    if (e >= E) return;
    int d = ei[E + e];
    int pos = atomicAdd(&cursor[d], 1);
    esrc[pos] = ei[e];
    ewt[pos] = ew[e];
}

// ================= gather propagate =================
// 4 rows per 256-block, 64 threads/row (wave-uniform trip count), float2/thread.
// If bnstats != nullptr, applies y = relu(v*scale + shift) to the gathered row
// elements before weighting (fused BN+ReLU of the source matrix).
__global__ __launch_bounds__(256) void gather_k(
    const float* __restrict__ h, const int* __restrict__ off,
    const int* __restrict__ esrc, const float* __restrict__ ewt,
    float* __restrict__ p, int N,
    const float* __restrict__ bnstats, const float* __restrict__ g,
    const float* __restrict__ be, float invN)
{
    int row = blockIdx.x * 4 + (threadIdx.x >> 6);
    if (row >= N) return;
    int lane = threadIdx.x & 63;
    int c0 = lane * 2;

    float sc0 = 1.f, sh0 = 0.f, sc1 = 1.f, sh1 = 0.f;
    bool bn = (bnstats != nullptr);
    if (bn) {
        float m0 = bnstats[c0] * invN;
        float v0 = bnstats[NF + c0] * invN - m0 * m0;
        float r0 = rsqrtf(v0 + 1e-5f) * g[c0];
        sc0 = r0; sh0 = be[c0] - m0 * r0;
        float m1 = bnstats[c0 + 1] * invN;
        float v1 = bnstats[NF + c0 + 1] * invN - m1 * m1;
        float r1 = rsqrtf(v1 + 1e-5f) * g[c0 + 1];
        sc1 = r1; sh1 = be[c0 + 1] - m1 * r1;
    }

    int beg = off[row], end = off[row + 1];
    float ax = 0.f, ay = 0.f;
    for (int e = beg; e < end; ++e) {
        int s = esrc[e];
        float w = ewt[e];
        float2 v = *(const float2*)&h[(size_t)s * NF + c0];
        if (bn) {
            v.x = fmaxf(fmaf(v.x, sc0, sh0), 0.f);
            v.y = fmaxf(fmaf(v.y, sc1, sh1), 0.f);
        }
        ax = fmaf(v.x, w, ax);
        ay = fmaf(v.y, w, ay);
    }
    float2 out = {ax, ay};
    *(float2*)&p[(size_t)row * NF + c0] = out;
}

// ================= fp32 GEMM, C[N,M] = A[N,128] @ W[M,128]^T + b =================
// 64-row tile per block, K chunked by 64. Optional fused column sum/sumsq stats.
template <int M>
__global__ __launch_bounds__(256) void gemm_k128(
    const float* __restrict__ A, const float* __restrict__ W,
    const float* __restrict__ bias, float* __restrict__ C,
    int N, int relu, float* __restrict__ stats)
{
    constexpr int CPT = M / 16;       // 8 (M=128) or 4 (M=64)
    __shared__ float At[64][68];      // [k][row], padded; also reused as stats scratch
    __shared__ float Wt[64][M + 4];   // [k][col], padded

    const int tid  = threadIdx.x;
    const int row0 = blockIdx.x * 64;
    const int tr   = tid >> 4;
    const int tc   = tid & 15;

    float acc[4][CPT];
#pragma unroll
    for (int i = 0; i < 4; i++)
#pragma unroll
        for (int j = 0; j < CPT; j++) acc[i][j] = 0.f;

    for (int kc = 0; kc < 128; kc += 64) {
        for (int idx = tid; idx < M * 64; idx += 256) {
            int o = idx >> 6, k = idx & 63;
            Wt[k][o] = W[o * 128 + kc + k];
        }
        for (int idx = tid; idx < 64 * 64; idx += 256) {
            int r = idx >> 6, k = idx & 63;
            int gr = row0 + r;
            At[k][r] = (gr < N) ? A[(size_t)gr * 128 + kc + k] : 0.f;
        }
        __syncthreads();

#pragma unroll 8
        for (int k = 0; k < 64; ++k) {
            float4 a4 = *(const float4*)&At[k][tr * 4];
            float av[4] = {a4.x, a4.y, a4.z, a4.w};
            float wv[CPT];
            {
                float4 w0 = *(const float4*)&Wt[k][tc * CPT];
                wv[0] = w0.x; wv[1] = w0.y; wv[2] = w0.z; wv[3] = w0.w;
                if constexpr (CPT == 8) {
                    float4 w1 = *(const float4*)&Wt[k][tc * CPT + 4];
                    wv[4] = w1.x; wv[5] = w1.y; wv[6] = w1.z; wv[7] = w1.w;
                }
            }
#pragma unroll
            for (int i = 0; i < 4; i++)
#pragma unroll
                for (int j = 0; j < CPT; j++)
                    acc[i][j] = fmaf(av[i], wv[j], acc[i][j]);
        }
        __syncthreads();
    }

    float colsum[CPT], colsq[CPT];
#pragma unroll
    for (int j = 0; j < CPT; j++) { colsum[j] = 0.f; colsq[j] = 0.f; }

#pragma unroll
    for (int i = 0; i < 4; i++) {
        int gr = row0 + tr * 4 + i;
        if (gr >= N) continue;
#pragma unroll
        for (int j = 0; j < CPT; j++) {
            int col = tc * CPT + j;
            float v = acc[i][j] + bias[col];
            if (relu) v = fmaxf(v, 0.f);
            C[(size_t)gr * M + col] = v;
            colsum[j] += v;
            colsq[j]  += v * v;
        }
    }

    if (stats) {
        // reuse At LDS as [16][128] sum + [16][128] sumsq scratch (16KB < 17.4KB)
        float* ps  = &At[0][0];
        float* ps2 = ps + 16 * 128;
        __syncthreads();
#pragma unroll
        for (int j = 0; j < CPT; j++) {
            ps [tr * 128 + tc * CPT + j] = colsum[j];
            ps2[tr * 128 + tc * CPT + j] = colsq[j];
        }
        __syncthreads();
        if (tid < 128) {
            float a = 0.f, b = 0.f;
#pragma unroll
            for (int t = 0; t < 16; t++) {
                a += ps [t * 128 + tid];
                b += ps2[t * 128 + tid];
            }
            unsafeAtomicAdd(&stats[tid], a);
            unsafeAtomicAdd(&stats[NF + tid], b);
        }
    }
}

// ================= BN + affine + ReLU (standalone, for layer 2 output) =========
__global__ __launch_bounds__(256) void bn_relu_k(
    const float* __restrict__ src, const float* __restrict__ stats,
    const float* __restrict__ g, const float* __restrict__ be,
    float* __restrict__ dst, int total, float invN)
{
    int idx = blockIdx.x * 256 + threadIdx.x;
    if (idx >= total) return;
    int col = idx & 127;
    float m   = stats[col] * invN;
    float var = stats[NF + col] * invN - m * m;
    float rs  = rsqrtf(var + 1e-5f);
    float v   = (src[idx] - m) * rs * g[col] + be[col];
    dst[idx] = fmaxf(v, 0.f);
}

extern "C" void kernel_launch(void* const* d_in, const int* in_sizes, int n_in,
                              void* d_out, int out_size, void* d_ws, size_t ws_size,
                              hipStream_t stream)
{
    const float* x   = (const float*)d_in[0];
    const int*   ei  = (const int*)d_in[1];
    const float* ew  = (const float*)d_in[2];
    const float* W1  = (const float*)d_in[3];
    const float* b1  = (const float*)d_in[4];
    const float* W2  = (const float*)d_in[5];
    const float* b2  = (const float*)d_in[6];
    const float* W3  = (const float*)d_in[7];
    const float* b3  = (const float*)d_in[8];
    const float* g1  = (const float*)d_in[9];
    const float* be1 = (const float*)d_in[10];
    const float* g2  = (const float*)d_in[11];
    const float* be2 = (const float*)d_in[12];
    const float* pW1 = (const float*)d_in[13];
    const float* pb1 = (const float*)d_in[14];
    const float* pW2 = (const float*)d_in[15];
    const float* pb2 = (const float*)d_in[16];

    const int N = in_sizes[0] / NF;
    const int E = in_sizes[2];

    float* out_logits = (float*)d_out;
    float* out_h      = out_logits + (size_t)N * 64;
    float* out_z      = out_h + (size_t)N * NF;

    // workspace layout
    float* p      = (float*)d_ws;              // N*128
    float* hpre   = p + (size_t)N * NF;        // N*128
    float* stats1 = hpre + (size_t)N * NF;     // 256
    float* stats2 = stats1 + 256;              // 256
    int*   deg    = (int*)(stats2 + 256);      // N
    int*   off    = deg + N;                   // N+1
    int*   cursor = off + N + 1;               // N
    int*   bsum   = cursor + N;                // 128
    int*   esrc   = bsum + 128;                // E
    float* ewt    = (float*)(esrc + E);        // E

    const int NB = (N + 1023) / 1024;
    const int ggrid = (N + 63) / 64;
    const int egrid = (N * NF + 255) / 256;
    const int pgrid = (N + 3) / 4;
    const float invN = 1.f / (float)N;

    // ---- CSR build ----
    hipMemsetAsync(deg, 0, (size_t)N * sizeof(int), stream);
    deg_k<<<(E + 255) / 256, 256, 0, stream>>>(ei, deg, E);
    scan1_k<<<NB, 256, 0, stream>>>(deg, off, bsum, N);
    scan2_k<<<1, 256, 0, stream>>>(bsum, NB);
    scan3_k<<<(N + 255) / 256, 256, 0, stream>>>(off, cursor, bsum, N, E);
    fill_k<<<(E + 255) / 256, 256, 0, stream>>>(ei, ew, cursor, esrc, ewt, E);

    // ---- layer 1 ----
    gather_k<<<pgrid, 256, 0, stream>>>(x, off, esrc, ewt, p, N,
                                        nullptr, nullptr, nullptr, 0.f);
    hipMemsetAsync(stats1, 0, 2 * NF * sizeof(float), stream);
    gemm_k128<128><<<ggrid, 256, 0, stream>>>(p, W1, b1, hpre, N, 0, stats1);

    // ---- layer 2 (BN1+ReLU fused into gather load) ----
    gather_k<<<pgrid, 256, 0, stream>>>(hpre, off, esrc, ewt, p, N,
                                        stats1, g1, be1, invN);
    hipMemsetAsync(stats2, 0, 2 * NF * sizeof(float), stream);
    gemm_k128<128><<<ggrid, 256, 0, stream>>>(p, W2, b2, hpre, N, 0, stats2);
    bn_relu_k<<<egrid, 256, 0, stream>>>(hpre, stats2, g2, be2, out_h, N * NF, invN);

    // ---- proj MLP ----
    gemm_k128<128><<<ggrid, 256, 0, stream>>>(out_h, pW1, pb1, hpre, N, 1, nullptr);
    gemm_k128<128><<<ggrid, 256, 0, stream>>>(hpre, pW2, pb2, out_z, N, 0, nullptr);

    // ---- logits ----
    gather_k<<<pgrid, 256, 0, stream>>>(out_h, off, esrc, ewt, p, N,
                                        nullptr, nullptr, nullptr, 0.f);
    gemm_k128<64><<<ggrid, 256, 0, stream>>>(p, W3, b3, out_logits, N, 0, nullptr);
}

// Round 3
// 1007.462 us; speedup vs baseline: 2.8163x; 1.2627x over previous
//
#include <hip/hip_runtime.h>

// SGGCN forward, CSR-gather version, round 3:
//  - gather: 4-edge batched (4 independent row loads in flight), packed (src,w) int2
//  - GEMM: 128x128 tile, 8x8/thread, wave-per-64x64-quadrant (2-way LDS alias = free)
//  - BN stats fused into GEMM epilogue; BN1+ReLU fused into gather #2 load

#define NF 128

// ================= CSR build =================
__global__ __launch_bounds__(256) void deg_k(const int* __restrict__ ei,
                                             int* __restrict__ deg, int E)
{
    int e = blockIdx.x * 256 + threadIdx.x;
    if (e < E) atomicAdd(&deg[ei[E + e]], 1);
}

__global__ __launch_bounds__(256) void scan1_k(const int* __restrict__ deg,
                                               int* __restrict__ off,
                                               int* __restrict__ bsum, int N)
{
    __shared__ int part[256];
    int t = threadIdx.x;
    int base = blockIdx.x * 1024 + t * 4;
    int v[4], s = 0;
#pragma unroll
    for (int i = 0; i < 4; i++) {
        int idx = base + i;
        v[i] = (idx < N) ? deg[idx] : 0;
        s += v[i];
    }
    part[t] = s;
    __syncthreads();
    for (int ofs = 1; ofs < 256; ofs <<= 1) {
        int x = (t >= ofs) ? part[t - ofs] : 0;
        __syncthreads();
        part[t] += x;
        __syncthreads();
    }
    int run = part[t] - s;
#pragma unroll
    for (int i = 0; i < 4; i++) {
        int idx = base + i;
        if (idx < N) off[idx] = run;
        run += v[i];
    }
    if (t == 0) bsum[blockIdx.x] = part[255];
}

__global__ void scan2_k(int* __restrict__ bsum, int NB)
{
    __shared__ int tmp[256];
    int t = threadIdx.x;
    if (t < NB) tmp[t] = bsum[t];
    __syncthreads();
    if (t == 0) {
        int acc = 0;
        for (int i = 0; i < NB; i++) { int x = tmp[i]; tmp[i] = acc; acc += x; }
    }
    __syncthreads();
    if (t < NB) bsum[t] = tmp[t];
}

__global__ __launch_bounds__(256) void scan3_k(int* __restrict__ off,
                                               int* __restrict__ cursor,
                                               const int* __restrict__ bsum,
                                               int N, int E)
{
    int idx = blockIdx.x * 256 + threadIdx.x;
    if (idx < N) {
        int o = off[idx] + bsum[idx >> 10];
        off[idx] = o;
        cursor[idx] = o;
    }
    if (idx == 0) off[N] = E;
}

__global__ __launch_bounds__(256) void fill_k(const int* __restrict__ ei,
                                              const float* __restrict__ ew,
                                              int* __restrict__ cursor,
                                              int2* __restrict__ epk, int E)
{
    int e = blockIdx.x * 256 + threadIdx.x;
    if (e >= E) return;
    int d = ei[E + e];
    int pos = atomicAdd(&cursor[d], 1);
    int2 q;
    q.x = ei[e];
    q.y = __float_as_int(ew[e]);
    epk[pos] = q;
}

// ================= gather propagate (4-edge batched) =================
// one 64-lane wave per dst row, float2/lane; 4 rows per 256-block.
__global__ __launch_bounds__(256) void gather_k(
    const float* __restrict__ h, const int* __restrict__ off,
    const int2* __restrict__ epk, float* __restrict__ p, int N,
    const float* __restrict__ bnstats, const float* __restrict__ g,
    const float* __restrict__ be, float invN)
{
    int row = blockIdx.x * 4 + (threadIdx.x >> 6);
    if (row >= N) return;
    int lane = threadIdx.x & 63;
    int c0 = lane * 2;

    float sc0 = 1.f, sh0 = 0.f, sc1 = 1.f, sh1 = 0.f;
    const bool bn = (bnstats != nullptr);
    if (bn) {
        float m0 = bnstats[c0] * invN;
        float v0 = bnstats[NF + c0] * invN - m0 * m0;
        float r0 = rsqrtf(v0 + 1e-5f) * g[c0];
        sc0 = r0; sh0 = be[c0] - m0 * r0;
        float m1 = bnstats[c0 + 1] * invN;
        float v1 = bnstats[NF + c0 + 1] * invN - m1 * m1;
        float r1 = rsqrtf(v1 + 1e-5f) * g[c0 + 1];
        sc1 = r1; sh1 = be[c0 + 1] - m1 * r1;
    }

    int beg = off[row], end = off[row + 1];
    float ax = 0.f, ay = 0.f;
    int e = beg;
    for (; e + 4 <= end; e += 4) {
        int2 q0 = epk[e + 0];
        int2 q1 = epk[e + 1];
        int2 q2 = epk[e + 2];
        int2 q3 = epk[e + 3];
        float2 v0 = *(const float2*)&h[(size_t)q0.x * NF + c0];
        float2 v1 = *(const float2*)&h[(size_t)q1.x * NF + c0];
        float2 v2 = *(const float2*)&h[(size_t)q2.x * NF + c0];
        float2 v3 = *(const float2*)&h[(size_t)q3.x * NF + c0];
        if (bn) {
            v0.x = fmaxf(fmaf(v0.x, sc0, sh0), 0.f); v0.y = fmaxf(fmaf(v0.y, sc1, sh1), 0.f);
            v1.x = fmaxf(fmaf(v1.x, sc0, sh0), 0.f); v1.y = fmaxf(fmaf(v1.y, sc1, sh1), 0.f);
            v2.x = fmaxf(fmaf(v2.x, sc0, sh0), 0.f); v2.y = fmaxf(fmaf(v2.y, sc1, sh1), 0.f);
            v3.x = fmaxf(fmaf(v3.x, sc0, sh0), 0.f); v3.y = fmaxf(fmaf(v3.y, sc1, sh1), 0.f);
        }
        float w0 = __int_as_float(q0.y), w1 = __int_as_float(q1.y);
        float w2 = __int_as_float(q2.y), w3 = __int_as_float(q3.y);
        ax = fmaf(v0.x, w0, ax); ay = fmaf(v0.y, w0, ay);
        ax = fmaf(v1.x, w1, ax); ay = fmaf(v1.y, w1, ay);
        ax = fmaf(v2.x, w2, ax); ay = fmaf(v2.y, w2, ay);
        ax = fmaf(v3.x, w3, ax); ay = fmaf(v3.y, w3, ay);
    }
    for (; e < end; ++e) {
        int2 q = epk[e];
        float w = __int_as_float(q.y);
        float2 v = *(const float2*)&h[(size_t)q.x * NF + c0];
        if (bn) {
            v.x = fmaxf(fmaf(v.x, sc0, sh0), 0.f);
            v.y = fmaxf(fmaf(v.y, sc1, sh1), 0.f);
        }
        ax = fmaf(v.x, w, ax);
        ay = fmaf(v.y, w, ay);
    }
    float2 out; out.x = ax; out.y = ay;
    *(float2*)&p[(size_t)row * NF + c0] = out;
}

// ================= fp32 GEMM, C[N,M] = A[N,128] @ W[M,128]^T + b =================
// 128-row tile, M cols, 8x8 (M=128) or 4x8 (M=64) per thread, K chunks of 32.
template <int M>
__global__ __launch_bounds__(256) void gemm_k(
    const float* __restrict__ A, const float* __restrict__ W,
    const float* __restrict__ bias, float* __restrict__ C,
    int N, int relu, float* __restrict__ stats)
{
    constexpr int KC  = 32;
    constexpr int RPT = (M == 128) ? 8 : 4;
    __shared__ float At[KC][132];
    __shared__ float Wt[KC][M + 4];

    const int tid  = threadIdx.x;
    const int row0 = blockIdx.x * 128;

    int r0, c0;
    if constexpr (M == 128) {
        // wave -> 64x64 quadrant; lane: ty=lane>>3 (8 rows), tx=lane&7 (8 cols)
        int wid = tid >> 6, lane = tid & 63;
        r0 = (wid >> 1) * 64 + (lane >> 3) * 8;
        c0 = (wid & 1) * 64 + (lane & 7) * 8;
    } else {
        r0 = (tid >> 3) * 4;   // 32 row-groups x 4 rows = 128 rows
        c0 = (tid & 7) * 8;    // 8 col-groups x 8 cols = 64 cols
    }

    float acc[RPT][8];
#pragma unroll
    for (int i = 0; i < RPT; i++)
#pragma unroll
        for (int j = 0; j < 8; j++) acc[i][j] = 0.f;

    for (int kc = 0; kc < 128; kc += KC) {
        // stage W chunk transposed: [k][col]
        for (int idx = tid; idx < M * (KC / 4); idx += 256) {
            int o = idx >> 3, k4 = idx & 7;
            float4 w4 = *(const float4*)&W[o * 128 + kc + k4 * 4];
            Wt[k4 * 4 + 0][o] = w4.x;
            Wt[k4 * 4 + 1][o] = w4.y;
            Wt[k4 * 4 + 2][o] = w4.z;
            Wt[k4 * 4 + 3][o] = w4.w;
        }
        // stage A tile transposed: [k][row]
        for (int idx = tid; idx < 128 * (KC / 4); idx += 256) {
            int r = idx >> 3, k4 = idx & 7;
            int gr = row0 + r;
            float4 a4 = make_float4(0.f, 0.f, 0.f, 0.f);
            if (gr < N) a4 = *(const float4*)&A[(size_t)gr * 128 + kc + k4 * 4];
            At[k4 * 4 + 0][r] = a4.x;
            At[k4 * 4 + 1][r] = a4.y;
            At[k4 * 4 + 2][r] = a4.z;
            At[k4 * 4 + 3][r] = a4.w;
        }
        __syncthreads();

#pragma unroll 4
        for (int k = 0; k < KC; ++k) {
            float av[RPT], wv[8];
            *(float4*)&av[0] = *(const float4*)&At[k][r0];
            if constexpr (RPT == 8)
                *(float4*)&av[4] = *(const float4*)&At[k][r0 + 4];
            *(float4*)&wv[0] = *(const float4*)&Wt[k][c0];
            *(float4*)&wv[4] = *(const float4*)&Wt[k][c0 + 4];
#pragma unroll
            for (int i = 0; i < RPT; i++)
#pragma unroll
                for (int j = 0; j < 8; j++)
                    acc[i][j] = fmaf(av[i], wv[j], acc[i][j]);
        }
        __syncthreads();
    }

    float bcol[8];
#pragma unroll
    for (int j = 0; j < 8; j++) bcol[j] = bias[c0 + j];

    float colsum[8], colsq[8];
#pragma unroll
    for (int j = 0; j < 8; j++) { colsum[j] = 0.f; colsq[j] = 0.f; }

#pragma unroll
    for (int i = 0; i < RPT; i++) {
        int gr = row0 + r0 + i;
        if (gr >= N) continue;
        float vals[8];
#pragma unroll
        for (int j = 0; j < 8; j++) {
            float v = acc[i][j] + bcol[j];
            if (relu) v = fmaxf(v, 0.f);
            vals[j] = v;
            colsum[j] += v;
            colsq[j]  += v * v;
        }
        *(float4*)&C[(size_t)gr * M + c0]     = *(float4*)&vals[0];
        *(float4*)&C[(size_t)gr * M + c0 + 4] = *(float4*)&vals[4];
    }

    if (stats) {
        // reduce 16 row-groups x 128 cols via LDS (reuse At: 16KB < 16.9KB)
        float* ps  = &At[0][0];
        float* ps2 = ps + 16 * 128;
        int wid = tid >> 6, lane = tid & 63;
        int rg = (wid >> 1) * 8 + (lane >> 3);  // 0..15 (M=128 mapping)
        __syncthreads();
#pragma unroll
        for (int j = 0; j < 8; j++) {
            ps [rg * 128 + c0 + j] = colsum[j];
            ps2[rg * 128 + c0 + j] = colsq[j];
        }
        __syncthreads();
        if (tid < 128) {
            float a = 0.f, b = 0.f;
#pragma unroll
            for (int t = 0; t < 16; t++) {
                a += ps [t * 128 + tid];
                b += ps2[t * 128 + tid];
            }
            unsafeAtomicAdd(&stats[tid], a);
            unsafeAtomicAdd(&stats[NF + tid], b);
        }
    }
}

// ================= BN + affine + ReLU (float4) =================
__global__ __launch_bounds__(256) void bn_relu_k(
    const float* __restrict__ src, const float* __restrict__ stats,
    const float* __restrict__ g, const float* __restrict__ be,
    float* __restrict__ dst, int total4, float invN)
{
    int idx = blockIdx.x * 256 + threadIdx.x;
    if (idx >= total4) return;
    int c = (idx * 4) & 127;
    float4 s = *(const float4*)&src[(size_t)idx * 4];
    float o[4] = {s.x, s.y, s.z, s.w};
#pragma unroll
    for (int i = 0; i < 4; i++) {
        float m   = stats[c + i] * invN;
        float var = stats[NF + c + i] * invN - m * m;
        float rs  = rsqrtf(var + 1e-5f);
        o[i] = fmaxf((o[i] - m) * rs * g[c + i] + be[c + i], 0.f);
    }
    float4 r; r.x = o[0]; r.y = o[1]; r.z = o[2]; r.w = o[3];
    *(float4*)&dst[(size_t)idx * 4] = r;
}

extern "C" void kernel_launch(void* const* d_in, const int* in_sizes, int n_in,
                              void* d_out, int out_size, void* d_ws, size_t ws_size,
                              hipStream_t stream)
{
    const float* x   = (const float*)d_in[0];
    const int*   ei  = (const int*)d_in[1];
    const float* ew  = (const float*)d_in[2];
    const float* W1  = (const float*)d_in[3];
    const float* b1  = (const float*)d_in[4];
    const float* W2  = (const float*)d_in[5];
    const float* b2  = (const float*)d_in[6];
    const float* W3  = (const float*)d_in[7];
    const float* b3  = (const float*)d_in[8];
    const float* g1  = (const float*)d_in[9];
    const float* be1 = (const float*)d_in[10];
    const float* g2  = (const float*)d_in[11];
    const float* be2 = (const float*)d_in[12];
    const float* pW1 = (const float*)d_in[13];
    const float* pb1 = (const float*)d_in[14];
    const float* pW2 = (const float*)d_in[15];
    const float* pb2 = (const float*)d_in[16];

    const int N = in_sizes[0] / NF;
    const int E = in_sizes[2];

    float* out_logits = (float*)d_out;
    float* out_h      = out_logits + (size_t)N * 64;
    float* out_z      = out_h + (size_t)N * NF;

    // workspace layout: epk first (8B aligned)
    int2*  epk    = (int2*)d_ws;                    // E
    float* p      = (float*)(epk + E);              // N*128
    float* hpre   = p + (size_t)N * NF;             // N*128
    float* stats1 = hpre + (size_t)N * NF;          // 256
    float* stats2 = stats1 + 256;                   // 256
    int*   deg    = (int*)(stats2 + 256);           // N
    int*   off    = deg + N;                        // N+1
    int*   cursor = off + N + 1;                    // N
    int*   bsum   = cursor + N;                     // NB (<=128)

    const int NB = (N + 1023) / 1024;
    const int ggrid = (N + 127) / 128;
    const int pgrid = (N + 3) / 4;
    const int e4grid = (N * NF / 4 + 255) / 256;
    const float invN = 1.f / (float)N;

    // ---- CSR build ----
    hipMemsetAsync(deg, 0, (size_t)N * sizeof(int), stream);
    deg_k<<<(E + 255) / 256, 256, 0, stream>>>(ei, deg, E);
    scan1_k<<<NB, 256, 0, stream>>>(deg, off, bsum, N);
    scan2_k<<<1, 256, 0, stream>>>(bsum, NB);
    scan3_k<<<(N + 255) / 256, 256, 0, stream>>>(off, cursor, bsum, N, E);
    fill_k<<<(E + 255) / 256, 256, 0, stream>>>(ei, ew, cursor, epk, E);

    // ---- layer 1 ----
    gather_k<<<pgrid, 256, 0, stream>>>(x, off, epk, p, N,
                                        nullptr, nullptr, nullptr, 0.f);
    hipMemsetAsync(stats1, 0, 2 * NF * sizeof(float), stream);
    gemm_k<128><<<ggrid, 256, 0, stream>>>(p, W1, b1, hpre, N, 0, stats1);

    // ---- layer 2 (BN1+ReLU fused into gather load) ----
    gather_k<<<pgrid, 256, 0, stream>>>(hpre, off, epk, p, N,
                                        stats1, g1, be1, invN);
    hipMemsetAsync(stats2, 0, 2 * NF * sizeof(float), stream);
    gemm_k<128><<<ggrid, 256, 0, stream>>>(p, W2, b2, hpre, N, 0, stats2);
    bn_relu_k<<<e4grid, 256, 0, stream>>>(hpre, stats2, g2, be2, out_h, N * NF / 4, invN);

    // ---- proj MLP ----
    gemm_k<128><<<ggrid, 256, 0, stream>>>(out_h, pW1, pb1, hpre, N, 1, nullptr);
    gemm_k<128><<<ggrid, 256, 0, stream>>>(hpre, pW2, pb2, out_z, N, 0, nullptr);

    // ---- logits ----
    gather_k<<<pgrid, 256, 0, stream>>>(out_h, off, epk, p, N,
                                        nullptr, nullptr, nullptr, 0.f);
    gemm_k<64><<<ggrid, 256, 0, stream>>>(p, W3, b3, out_logits, N, 0, nullptr);
}

// Round 4
// 798.976 us; speedup vs baseline: 3.5512x; 1.2609x over previous
//
#include <hip/hip_runtime.h>

// SGGCN forward, round 4: bf16 storage + MFMA GEMMs + propagate/W3 commutation.
//  - all N*128 intermediates bf16 (halves gather traffic)
//  - GEMMs: mfma_f32_16x16x32_bf16, fragments loaded straight from global
//    (A row-major bf16 is frag-native; W pre-converted to frag-ordered layout)
//  - logits = propagate(h @ W3^T) + b3  (exact: propagate is linear)

#define NF 128

using short8 = __attribute__((ext_vector_type(8))) short;
using f32x4  = __attribute__((ext_vector_type(4))) float;

__device__ __forceinline__ float b2f(unsigned short u) {
    return __uint_as_float(((unsigned)u) << 16);
}
__device__ __forceinline__ unsigned short f2b(float f) {
    unsigned u = __float_as_uint(f);
    u += 0x7fff + ((u >> 16) & 1);          // RNE
    return (unsigned short)(u >> 16);
}

// ================= CSR build =================
__global__ __launch_bounds__(256) void deg_k(const int* __restrict__ ei,
                                             int* __restrict__ deg, int E)
{
    int e = blockIdx.x * 256 + threadIdx.x;
    if (e < E) atomicAdd(&deg[ei[E + e]], 1);
}

__global__ __launch_bounds__(256) void scan1_k(const int* __restrict__ deg,
                                               int* __restrict__ off,
                                               int* __restrict__ bsum, int N)
{
    __shared__ int part[256];
    int t = threadIdx.x;
    int base = blockIdx.x * 1024 + t * 4;
    int v[4], s = 0;
#pragma unroll
    for (int i = 0; i < 4; i++) {
        int idx = base + i;
        v[i] = (idx < N) ? deg[idx] : 0;
        s += v[i];
    }
    part[t] = s;
    __syncthreads();
    for (int ofs = 1; ofs < 256; ofs <<= 1) {
        int x = (t >= ofs) ? part[t - ofs] : 0;
        __syncthreads();
        part[t] += x;
        __syncthreads();
    }
    int run = part[t] - s;
#pragma unroll
    for (int i = 0; i < 4; i++) {
        int idx = base + i;
        if (idx < N) off[idx] = run;
        run += v[i];
    }
    if (t == 0) bsum[blockIdx.x] = part[255];
}

__global__ void scan2_k(int* __restrict__ bsum, int NB)
{
    __shared__ int tmp[256];
    int t = threadIdx.x;
    if (t < NB) tmp[t] = bsum[t];
    __syncthreads();
    if (t == 0) {
        int acc = 0;
        for (int i = 0; i < NB; i++) { int x = tmp[i]; tmp[i] = acc; acc += x; }
    }
    __syncthreads();
    if (t < NB) bsum[t] = tmp[t];
}

__global__ __launch_bounds__(256) void scan3_k(int* __restrict__ off,
                                               int* __restrict__ cursor,
                                               const int* __restrict__ bsum,
                                               int N, int E)
{
    int idx = blockIdx.x * 256 + threadIdx.x;
    if (idx < N) {
        int o = off[idx] + bsum[idx >> 10];
        off[idx] = o;
        cursor[idx] = o;
    }
    if (idx == 0) off[N] = E;
}

__global__ __launch_bounds__(256) void fill_k(const int* __restrict__ ei,
                                              const float* __restrict__ ew,
                                              int* __restrict__ cursor,
                                              int2* __restrict__ epk, int E)
{
    int e = blockIdx.x * 256 + threadIdx.x;
    if (e >= E) return;
    int d = ei[E + e];
    int pos = atomicAdd(&cursor[d], 1);
    int2 q;
    q.x = ei[e];
    q.y = __float_as_int(ew[e]);
    epk[pos] = q;
}

// ================= converts =================
__global__ __launch_bounds__(256) void convx_k(const float* __restrict__ x,
                                               unsigned short* __restrict__ xb,
                                               int total4)
{
    int idx = blockIdx.x * 256 + threadIdx.x;
    if (idx >= total4) return;
    float4 v = *(const float4*)&x[(size_t)idx * 4];
    ushort4 o;
    o.x = f2b(v.x); o.y = f2b(v.y); o.z = f2b(v.z); o.w = f2b(v.w);
    *(ushort4*)&xb[(size_t)idx * 4] = o;
}

// W [M][128] fp32 -> frag-ordered bf16: Wb[((nb*4+ks)*64 + lane)*8 + j]
//   = W[nb*16 + (lane&15)][ks*32 + (lane>>4)*8 + j]
__global__ __launch_bounds__(64) void convw_k(const float* __restrict__ W,
                                              unsigned short* __restrict__ Wb)
{
    int lane = threadIdx.x;
    int nb = blockIdx.x >> 2, ks = blockIdx.x & 3;
    const float* src = W + (size_t)(nb * 16 + (lane & 15)) * 128 + ks * 32 + (lane >> 4) * 8;
    unsigned short* dst = Wb + ((size_t)blockIdx.x * 64 + lane) * 8;
#pragma unroll
    for (int j = 0; j < 8; j++) dst[j] = f2b(src[j]);
}

// ================= gather propagate (bf16 in/out, 128 cols) =================
__global__ __launch_bounds__(256) void gather_k(
    const unsigned short* __restrict__ h, const int* __restrict__ off,
    const int2* __restrict__ epk, unsigned short* __restrict__ p, int N,
    const float* __restrict__ bnstats, const float* __restrict__ g,
    const float* __restrict__ be, float invN)
{
    int row = blockIdx.x * 4 + (threadIdx.x >> 6);
    if (row >= N) return;
    int lane = threadIdx.x & 63;
    int c0 = lane * 2;

    float sc0 = 1.f, sh0 = 0.f, sc1 = 1.f, sh1 = 0.f;
    const bool bn = (bnstats != nullptr);
    if (bn) {
        float m0 = bnstats[c0] * invN;
        float v0 = bnstats[NF + c0] * invN - m0 * m0;
        float r0 = rsqrtf(v0 + 1e-5f) * g[c0];
        sc0 = r0; sh0 = be[c0] - m0 * r0;
        float m1 = bnstats[c0 + 1] * invN;
        float v1 = bnstats[NF + c0 + 1] * invN - m1 * m1;
        float r1 = rsqrtf(v1 + 1e-5f) * g[c0 + 1];
        sc1 = r1; sh1 = be[c0 + 1] - m1 * r1;
    }

    int beg = off[row], end = off[row + 1];
    float ax = 0.f, ay = 0.f;
    int e = beg;
    for (; e + 4 <= end; e += 4) {
        int2 q0 = epk[e + 0], q1 = epk[e + 1], q2 = epk[e + 2], q3 = epk[e + 3];
        ushort2 u0 = *(const ushort2*)&h[(size_t)q0.x * NF + c0];
        ushort2 u1 = *(const ushort2*)&h[(size_t)q1.x * NF + c0];
        ushort2 u2 = *(const ushort2*)&h[(size_t)q2.x * NF + c0];
        ushort2 u3 = *(const ushort2*)&h[(size_t)q3.x * NF + c0];
        float v0x = b2f(u0.x), v0y = b2f(u0.y);
        float v1x = b2f(u1.x), v1y = b2f(u1.y);
        float v2x = b2f(u2.x), v2y = b2f(u2.y);
        float v3x = b2f(u3.x), v3y = b2f(u3.y);
        if (bn) {
            v0x = fmaxf(fmaf(v0x, sc0, sh0), 0.f); v0y = fmaxf(fmaf(v0y, sc1, sh1), 0.f);
            v1x = fmaxf(fmaf(v1x, sc0, sh0), 0.f); v1y = fmaxf(fmaf(v1y, sc1, sh1), 0.f);
            v2x = fmaxf(fmaf(v2x, sc0, sh0), 0.f); v2y = fmaxf(fmaf(v2y, sc1, sh1), 0.f);
            v3x = fmaxf(fmaf(v3x, sc0, sh0), 0.f); v3y = fmaxf(fmaf(v3y, sc1, sh1), 0.f);
        }
        float w0 = __int_as_float(q0.y), w1 = __int_as_float(q1.y);
        float w2 = __int_as_float(q2.y), w3 = __int_as_float(q3.y);
        ax = fmaf(v0x, w0, ax); ay = fmaf(v0y, w0, ay);
        ax = fmaf(v1x, w1, ax); ay = fmaf(v1y, w1, ay);
        ax = fmaf(v2x, w2, ax); ay = fmaf(v2y, w2, ay);
        ax = fmaf(v3x, w3, ax); ay = fmaf(v3y, w3, ay);
    }
    for (; e < end; ++e) {
        int2 q = epk[e];
        float w = __int_as_float(q.y);
        ushort2 u = *(const ushort2*)&h[(size_t)q.x * NF + c0];
        float vx = b2f(u.x), vy = b2f(u.y);
        if (bn) {
            vx = fmaxf(fmaf(vx, sc0, sh0), 0.f);
            vy = fmaxf(fmaf(vy, sc1, sh1), 0.f);
        }
        ax = fmaf(vx, w, ax);
        ay = fmaf(vy, w, ay);
    }
    ushort2 o; o.x = f2b(ax); o.y = f2b(ay);
    *(ushort2*)&p[(size_t)row * NF + c0] = o;
}

// ============== gather over 64-dim bf16 rows -> fp32 logits + bias =========
__global__ __launch_bounds__(256) void gather64_k(
    const unsigned short* __restrict__ y, const int* __restrict__ off,
    const int2* __restrict__ epk, const float* __restrict__ bias,
    float* __restrict__ out, int N)
{
    int row = blockIdx.x * 8 + (threadIdx.x >> 5);
    if (row >= N) return;
    int sub = threadIdx.x & 31;
    int c0 = sub * 2;

    int beg = off[row], end = off[row + 1];
    float ax = 0.f, ay = 0.f;
    int e = beg;
    for (; e + 4 <= end; e += 4) {
        int2 q0 = epk[e + 0], q1 = epk[e + 1], q2 = epk[e + 2], q3 = epk[e + 3];
        ushort2 u0 = *(const ushort2*)&y[(size_t)q0.x * 64 + c0];
        ushort2 u1 = *(const ushort2*)&y[(size_t)q1.x * 64 + c0];
        ushort2 u2 = *(const ushort2*)&y[(size_t)q2.x * 64 + c0];
        ushort2 u3 = *(const ushort2*)&y[(size_t)q3.x * 64 + c0];
        float w0 = __int_as_float(q0.y), w1 = __int_as_float(q1.y);
        float w2 = __int_as_float(q2.y), w3 = __int_as_float(q3.y);
        ax = fmaf(b2f(u0.x), w0, ax); ay = fmaf(b2f(u0.y), w0, ay);
        ax = fmaf(b2f(u1.x), w1, ax); ay = fmaf(b2f(u1.y), w1, ay);
        ax = fmaf(b2f(u2.x), w2, ax); ay = fmaf(b2f(u2.y), w2, ay);
        ax = fmaf(b2f(u3.x), w3, ax); ay = fmaf(b2f(u3.y), w3, ay);
    }
    for (; e < end; ++e) {
        int2 q = epk[e];
        float w = __int_as_float(q.y);
        ushort2 u = *(const ushort2*)&y[(size_t)q.x * 64 + c0];
        ax = fmaf(b2f(u.x), w, ax);
        ay = fmaf(b2f(u.y), w, ay);
    }
    float2 o; o.x = ax + bias[c0]; o.y = ay + bias[c0 + 1];
    *(float2*)&out[(size_t)row * 64 + c0] = o;
}

// ================= MFMA GEMM: C[N,M] = A[N,128]bf16 @ W[M,128]^T + b ==========
// 128-row block tile, 4 waves. M=128: wave -> 64x64 quadrant (4m x 4n 16-tiles).
// M=64: wave -> 32 rows x 64 cols (2m x 4n). Frags loaded straight from global.
// COUT: 0 = fp32 C, 1 = bf16 C. Optional fused column sum/sumsq stats.
template <int M, int COUT>
__global__ __launch_bounds__(256) void mgemm_k(
    const unsigned short* __restrict__ A, const unsigned short* __restrict__ Wb,
    const float* __restrict__ bias, void* __restrict__ Cp,
    int N, int relu, float* __restrict__ stats)
{
    constexpr int MI = (M == 128) ? 4 : 2;
    __shared__ float sbuf[256];

    const int tid = threadIdx.x, wid = tid >> 6, lane = tid & 63;
    const int quad = lane >> 4, l16 = lane & 15;
    const int rowBase = blockIdx.x * 128;
    int r0, c0;
    if constexpr (M == 128) { r0 = (wid >> 1) * 64; c0 = (wid & 1) * 64; }
    else                    { r0 = wid * 32;        c0 = 0; }

    f32x4 acc[MI][4];
#pragma unroll
    for (int mi = 0; mi < MI; mi++)
#pragma unroll
        for (int ni = 0; ni < 4; ni++)
#pragma unroll
            for (int r = 0; r < 4; r++) acc[mi][ni][r] = 0.f;

#pragma unroll
    for (int ks = 0; ks < 4; ++ks) {
        short8 af[MI], bf[4];
#pragma unroll
        for (int mi = 0; mi < MI; mi++) {
            int gr = rowBase + r0 + mi * 16 + l16;
            gr = (gr < N) ? gr : (N - 1);
            af[mi] = *(const short8*)(A + (size_t)gr * 128 + ks * 32 + quad * 8);
        }
#pragma unroll
        for (int ni = 0; ni < 4; ni++) {
            int nb = (c0 >> 4) + ni;
            bf[ni] = *(const short8*)(Wb + ((size_t)(nb * 4 + ks) * 64 + lane) * 8);
        }
#pragma unroll
        for (int mi = 0; mi < MI; mi++)
#pragma unroll
            for (int ni = 0; ni < 4; ni++)
                acc[mi][ni] = __builtin_amdgcn_mfma_f32_16x16x32_bf16(
                    af[mi], bf[ni], acc[mi][ni], 0, 0, 0);
    }

    float csum[4] = {0.f, 0.f, 0.f, 0.f}, csq[4] = {0.f, 0.f, 0.f, 0.f};
#pragma unroll
    for (int mi = 0; mi < MI; mi++) {
#pragma unroll
        for (int r = 0; r < 4; r++) {
            int gr = rowBase + r0 + mi * 16 + quad * 4 + r;
            if (gr >= N) continue;
#pragma unroll
            for (int ni = 0; ni < 4; ni++) {
                int col = c0 + ni * 16 + l16;
                float v = acc[mi][ni][r] + (bias ? bias[col] : 0.f);
                if (relu) v = fmaxf(v, 0.f);
                if constexpr (COUT == 1)
                    ((unsigned short*)Cp)[(size_t)gr * M + col] = f2b(v);
                else
                    ((float*)Cp)[(size_t)gr * M + col] = v;
                csum[ni] += v;
                csq[ni]  += v * v;
            }
        }
    }

    if (stats) {
        sbuf[tid] = 0.f;
        __syncthreads();
#pragma unroll
        for (int ni = 0; ni < 4; ni++) {
            int col = c0 + ni * 16 + l16;
            atomicAdd(&sbuf[col], csum[ni]);
            atomicAdd(&sbuf[128 + col], csq[ni]);
        }
        __syncthreads();
        if (tid < 128) {
            unsafeAtomicAdd(&stats[tid], sbuf[tid]);
            unsafeAtomicAdd(&stats[NF + tid], sbuf[128 + tid]);
        }
    }
}

// ======= BN2 + affine + ReLU: bf16 pre -> fp32 out_h AND bf16 hb ==========
__global__ __launch_bounds__(256) void bnrelu2_k(
    const unsigned short* __restrict__ pre, const float* __restrict__ stats,
    const float* __restrict__ g, const float* __restrict__ be,
    float* __restrict__ outh, unsigned short* __restrict__ hb,
    int total4, float invN)
{
    int idx = blockIdx.x * 256 + threadIdx.x;
    if (idx >= total4) return;
    int c = (idx * 4) & 127;
    ushort4 u = *(const ushort4*)&pre[(size_t)idx * 4];
    float in[4] = {b2f(u.x), b2f(u.y), b2f(u.z), b2f(u.w)};
    float o[4];
#pragma unroll
    for (int i = 0; i < 4; i++) {
        float m   = stats[c + i] * invN;
        float var = stats[NF + c + i] * invN - m * m;
        float rs  = rsqrtf(var + 1e-5f);
        o[i] = fmaxf((in[i] - m) * rs * g[c + i] + be[c + i], 0.f);
    }
    float4 f; f.x = o[0]; f.y = o[1]; f.z = o[2]; f.w = o[3];
    *(float4*)&outh[(size_t)idx * 4] = f;
    ushort4 h4;
    h4.x = f2b(o[0]); h4.y = f2b(o[1]); h4.z = f2b(o[2]); h4.w = f2b(o[3]);
    *(ushort4*)&hb[(size_t)idx * 4] = h4;
}

extern "C" void kernel_launch(void* const* d_in, const int* in_sizes, int n_in,
                              void* d_out, int out_size, void* d_ws, size_t ws_size,
                              hipStream_t stream)
{
    const float* x   = (const float*)d_in[0];
    const int*   ei  = (const int*)d_in[1];
    const float* ew  = (const float*)d_in[2];
    const float* W1  = (const float*)d_in[3];
    const float* b1  = (const float*)d_in[4];
    const float* W2  = (const float*)d_in[5];
    const float* b2  = (const float*)d_in[6];
    const float* W3  = (const float*)d_in[7];
    const float* b3  = (const float*)d_in[8];
    const float* g1  = (const float*)d_in[9];
    const float* be1 = (const float*)d_in[10];
    const float* g2  = (const float*)d_in[11];
    const float* be2 = (const float*)d_in[12];
    const float* pW1 = (const float*)d_in[13];
    const float* pb1 = (const float*)d_in[14];
    const float* pW2 = (const float*)d_in[15];
    const float* pb2 = (const float*)d_in[16];

    const int N = in_sizes[0] / NF;
    const int E = in_sizes[2];

    float* out_logits = (float*)d_out;
    float* out_h      = out_logits + (size_t)N * 64;
    float* out_z      = out_h + (size_t)N * NF;

    // ---- workspace layout ----
    const size_t rowsUS = (size_t)N * NF;          // ushorts per N*128 bf16 buf
    int2*           epk = (int2*)d_ws;                           // E*8 B
    unsigned short* B1  = (unsigned short*)(epk + E);            // xb -> pre2b
    unsigned short* B2  = B1 + rowsUS;                           // p0/p1 -> hb
    unsigned short* B3  = B2 + rowsUS;                           // pre1 -> y -> t
    float* stats1 = (float*)(B3 + rowsUS);                       // 256
    float* stats2 = stats1 + 256;                                // 256
    float* wconv  = stats2 + 256;            // 5 bf16 weight bufs (as ushort)
    unsigned short* W1b  = (unsigned short*)wconv;               // 128*128
    unsigned short* W2b  = W1b + 128 * 128;
    unsigned short* pW1b = W2b + 128 * 128;
    unsigned short* pW2b = pW1b + 128 * 128;
    unsigned short* W3b  = pW2b + 128 * 128;                     // 64*128
    int* deg    = (int*)(W3b + 64 * 128);
    int* off    = deg + N;
    int* cursor = off + N + 1;
    int* bsum   = cursor + N;

    const int NB = (N + 1023) / 1024;
    const int ggrid  = (N + 127) / 128;
    const int pgrid  = (N + 3) / 4;
    const int p8grid = (N + 7) / 8;
    const int c4grid = (N * NF / 4 + 255) / 256;
    const float invN = 1.f / (float)N;

    // ---- converts ----
    convx_k<<<c4grid, 256, 0, stream>>>(x, B1, N * NF / 4);
    convw_k<<<32, 64, 0, stream>>>(W1, W1b);
    convw_k<<<32, 64, 0, stream>>>(W2, W2b);
    convw_k<<<32, 64, 0, stream>>>(pW1, pW1b);
    convw_k<<<32, 64, 0, stream>>>(pW2, pW2b);
    convw_k<<<16, 64, 0, stream>>>(W3, W3b);

    // ---- CSR build ----
    hipMemsetAsync(deg, 0, (size_t)N * sizeof(int), stream);
    deg_k<<<(E + 255) / 256, 256, 0, stream>>>(ei, deg, E);
    scan1_k<<<NB, 256, 0, stream>>>(deg, off, bsum, N);
    scan2_k<<<1, 256, 0, stream>>>(bsum, NB);
    scan3_k<<<(N + 255) / 256, 256, 0, stream>>>(off, cursor, bsum, N, E);
    fill_k<<<(E + 255) / 256, 256, 0, stream>>>(ei, ew, cursor, epk, E);

    // ---- layer 1 ----
    gather_k<<<pgrid, 256, 0, stream>>>(B1, off, epk, B2, N,
                                        nullptr, nullptr, nullptr, 0.f);
    hipMemsetAsync(stats1, 0, 2 * NF * sizeof(float), stream);
    mgemm_k<128, 1><<<ggrid, 256, 0, stream>>>(B2, W1b, b1, B3, N, 0, stats1);

    // ---- layer 2 (BN1+ReLU fused into gather load) ----
    gather_k<<<pgrid, 256, 0, stream>>>(B3, off, epk, B2, N,
                                        stats1, g1, be1, invN);
    hipMemsetAsync(stats2, 0, 2 * NF * sizeof(float), stream);
    mgemm_k<128, 1><<<ggrid, 256, 0, stream>>>(B2, W2b, b2, B1, N, 0, stats2);

    // ---- BN2+ReLU -> out_h (fp32) + hb (bf16, into B2) ----
    bnrelu2_k<<<c4grid, 256, 0, stream>>>(B1, stats2, g2, be2, out_h, B2,
                                          N * NF / 4, invN);

    // ---- logits = propagate(h @ W3^T) + b3 ----
    mgemm_k<64, 1><<<ggrid, 256, 0, stream>>>(B2, W3b, nullptr, B3, N, 0, nullptr);
    gather64_k<<<p8grid, 256, 0, stream>>>(B3, off, epk, b3, out_logits, N);

    // ---- proj MLP: z = relu(h@pW1.T+pb1) @ pW2.T + pb2 ----
    mgemm_k<128, 1><<<ggrid, 256, 0, stream>>>(B2, pW1b, pb1, B3, N, 1, nullptr);
    mgemm_k<128, 0><<<ggrid, 256, 0, stream>>>(B3, pW2b, pb2, out_z, N, 0, nullptr);
}